// Round 5
// baseline (570.777 us; speedup 1.0000x reference)
//
#include <hip/hip_runtime.h>

// LSTM B=1024,T=512,F=40,H=50 via bf16 MFMA (mfma_f32_16x16x32_bf16).
// 256 blocks x 256 threads (4 waves); each block owns 4 batch rows inside a
// 16-row MFMA tile (rows 4-15 are zero padding -- wasted MFMA rows buy
// full-chip block coverage: M=16 would give only 64 blocks / 64 CUs).
// Per step: gates[16,208] = A_x[16,64]@Bx + A_h[16,64]@Bh (13 N-tiles x
// 4 K-chunks = 52 MFMAs, weights resident in B-fragments ~64 VGPRs),
// then 200 pointwise lanes do the cell update (c fp32 in registers),
// write h as bf16 into the A_h staging row. x double-buffered in LDS,
// prefetched 3 steps deep by lanes 200-239. fp32-VALU rounds r1-r4 were
// pinched between AGPR-spill VALU inflation and LDS-broadcast cost; MFMA
// removes both (fragment weights + 4 A-frag reads/wave-step).

constexpr int kBt = 1024;
constexpr int kT  = 512;
constexpr int kF  = 40;
constexpr int kH  = 50;
constexpr int kMB = 4;                 // real batches per block
constexpr int kRow = 80;               // A-row stride in shorts (160 B)
constexpr int kGS  = 212;              // gates row stride in dwords

typedef __attribute__((ext_vector_type(8))) short bf16x8;   // 8 bf16 = 4 VGPRs
typedef __attribute__((ext_vector_type(4))) short short4v;  // 8 B
typedef __attribute__((ext_vector_type(4))) float f32x4;

__device__ __forceinline__ unsigned short f2bf(float f) {
    union { float f; unsigned u; } v; v.f = f;
    return (unsigned short)((v.u + 0x7FFFu + ((v.u >> 16) & 1u)) >> 16);
}
__device__ __forceinline__ float fast_sigmoid(float v) {
    return __builtin_amdgcn_rcpf(1.f + __expf(-v));
}
__device__ __forceinline__ float fast_tanh(float v) {
    return 1.f - 2.f * __builtin_amdgcn_rcpf(__expf(2.f * v) + 1.f);
}

__global__ __attribute__((amdgpu_flat_work_group_size(256, 256),
                          amdgpu_waves_per_eu(1)))
void lstm_mfma(
    const float* __restrict__ x,      // [B,T,F]
    const float* __restrict__ W_ih,   // [4H,F]
    const float* __restrict__ W_hh,   // [4H,H]
    const float* __restrict__ b_ih,   // [4H]
    const float* __restrict__ b_hh,   // [4H]
    const float* __restrict__ W1,     // [10,H]
    const float* __restrict__ b1,     // [10]
    const float* __restrict__ W2,     // [1,10]
    const float* __restrict__ b2,     // [1]
    float* __restrict__ out)          // [B]
{
    const int tid  = threadIdx.x;
    const int lane = tid & 63;
    const int wave = tid >> 6;
    const int bb   = blockIdx.x;

    __shared__ short sh_ax[2][16 * kRow];   // x_t staging, bf16 A-layout rows
    __shared__ short sh_ah[16 * kRow];      // h staging, bf16 A-layout rows
    __shared__ float sh_g[16 * kGS];        // gate pre-activations [m][n]
    __shared__ float sh_hf[kMB][kH];        // final h in fp32 (head)
    __shared__ float sh_head[kMB][10];

    // ---- init: zero A staging (pads must stay 0 forever) ----
    {
        int* z = (int*)sh_ax;                        // 2*16*80 shorts = 1280 ints
        for (int i = tid; i < 1280; i += 256) z[i] = 0;
        int* z2 = (int*)sh_ah;                       // 640 ints
        for (int i = tid; i < 640; i += 256) z2[i] = 0;
    }

    // ---- B fragments: wave w owns N-tiles {w, w+4, w+8[, 12 for w==0]} ----
    const int ntile = (wave == 0) ? 4 : 3;
    const int fn = lane & 15;        // n within tile / m for A / col for D
    const int fq = lane >> 4;        // quad
    bf16x8 bx[4][2], bh[4][2];
#pragma unroll
    for (int i = 0; i < 4; ++i) {
        const int tau = wave + 4 * i;
        const int n = tau * 16 + fn;
        const bool live = (i < ntile);
#pragma unroll
        for (int kk = 0; kk < 2; ++kk) {
            bf16x8 vx, vh;
#pragma unroll
            for (int j = 0; j < 8; ++j) {
                const int k = kk * 32 + fq * 8 + j;
                float wx = (live && n < 200 && k < kF) ? W_ih[n * kF + k] : 0.f;
                float wh = (live && n < 200 && k < kH) ? W_hh[n * kH + k] : 0.f;
                vx[j] = (short)f2bf(wx);
                vh[j] = (short)f2bf(wh);
            }
            bx[i][kk] = vx;
            bh[i][kk] = vh;
        }
    }

    // ---- pointwise lane state (tid < 200): unit u of batch m ----
    const int pm = (tid < 200) ? (tid / 50) : 0;
    const int pu = (tid < 200) ? (tid % 50) : 0;
    float c = 0.f, bi = 0.f, bf_ = 0.f, bg = 0.f, bo = 0.f;
    if (tid < 200) {
        bi  = b_ih[pu]        + b_hh[pu];
        bf_ = b_ih[pu + 50]   + b_hh[pu + 50];
        bg  = b_ih[pu + 100]  + b_hh[pu + 100];
        bo  = b_ih[pu + 150]  + b_hh[pu + 150];
        c   = (pu == 0) ? 1.f : 0.f;
    }

    // ---- x prefetch lanes (200 <= tid < 240): batch hm, float4 chunk hq ----
    const int hidx = tid - 200;
    const int hm = hidx / 10, hq = hidx % 10;
    const float* xrow = x + (size_t)(bb * kMB + hm) * kT * kF + hq * 4;
    float4 px0 = make_float4(0, 0, 0, 0), px1 = px0, pxc = px0;
    if (tid >= 200 && tid < 240) {
        pxc = *(const float4*)(xrow);                 // x_0
        px0 = *(const float4*)(xrow + (size_t)1 * kF); // x_1
        px1 = *(const float4*)(xrow + (size_t)2 * kF); // x_2
    }
    __syncthreads();   // zero-init complete before staging writes
    if (tid >= 200 && tid < 240) {
        short4v w;
        w[0] = (short)f2bf(pxc.x); w[1] = (short)f2bf(pxc.y);
        w[2] = (short)f2bf(pxc.z); w[3] = (short)f2bf(pxc.w);
        *(short4v*)&sh_ax[0][hm * kRow + hq * 4] = w;
    }
    __syncthreads();

    // ================= time loop =================
    for (int t = 0; t < kT; ++t) {
        const short* axb = sh_ax[t & 1];

        // A fragments: lane holds A[m=fn][k = kk*32 + fq*8 + j]
        bf16x8 ax0 = *(const bf16x8*)&axb[fn * kRow +      fq * 8];
        bf16x8 ax1 = *(const bf16x8*)&axb[fn * kRow + 32 + fq * 8];
        bf16x8 ah0 = *(const bf16x8*)&sh_ah[fn * kRow +      fq * 8];
        bf16x8 ah1 = *(const bf16x8*)&sh_ah[fn * kRow + 32 + fq * 8];

#pragma unroll
        for (int i = 0; i < 4; ++i) {
            if (i < ntile) {                           // wave-uniform branch
                f32x4 d = {0.f, 0.f, 0.f, 0.f};
                d = __builtin_amdgcn_mfma_f32_16x16x32_bf16(ax0, bx[i][0], d, 0, 0, 0);
                d = __builtin_amdgcn_mfma_f32_16x16x32_bf16(ax1, bx[i][1], d, 0, 0, 0);
                d = __builtin_amdgcn_mfma_f32_16x16x32_bf16(ah0, bh[i][0], d, 0, 0, 0);
                d = __builtin_amdgcn_mfma_f32_16x16x32_bf16(ah1, bh[i][1], d, 0, 0, 0);
                // D: col n = lane&15, row m = fq*4 + r
                const int n = (wave + 4 * i) * 16 + fn;
#pragma unroll
                for (int r = 0; r < 4; ++r)
                    sh_g[(fq * 4 + r) * kGS + n] = d[r];
            }
        }
        __syncthreads();

        if (tid < 200) {
            const float* g = &sh_g[pm * kGS];
            float i_s = fast_sigmoid(g[pu]        + bi);
            float f_s = fast_sigmoid(g[pu + 50]   + bf_);
            float g_t = fast_tanh   (g[pu + 100]  + bg);
            float o_s = fast_sigmoid(g[pu + 150]  + bo);
            c = fmaf(f_s, c, i_s * g_t);
            float hv = o_s * fast_tanh(c);
            sh_ah[pm * kRow + pu] = (short)f2bf(hv);
            if (t == kT - 1) sh_hf[pm][pu] = hv;
        } else if (tid < 240) {
            // commit x_{t+1} into the other buffer; slide the 3-deep pipe
            short4v w;
            w[0] = (short)f2bf(px0.x); w[1] = (short)f2bf(px0.y);
            w[2] = (short)f2bf(px0.z); w[3] = (short)f2bf(px0.w);
            *(short4v*)&sh_ax[(t + 1) & 1][hm * kRow + hq * 4] = w;
            px0 = px1;
            if (t + 3 < kT) px1 = *(const float4*)(xrow + (size_t)(t + 3) * kF);
        }
        __syncthreads();
    }

    // ---- head: relu(h @ W1.T + b1) @ W2.T + b2 + x[b, T-1, 0] ----
    if (tid < 40) {
        const int m = tid / 10, j = tid % 10;
        float acc = b1[j];
#pragma unroll
        for (int k = 0; k < kH; ++k) acc = fmaf(sh_hf[m][k], W1[j * kH + k], acc);
        sh_head[m][j] = fmaxf(acc, 0.f);
    }
    __syncthreads();
    if (tid < kMB) {
        float acc = b2[0];
#pragma unroll
        for (int j = 0; j < 10; ++j) acc = fmaf(sh_head[tid][j], W2[j], acc);
        const int bidx = bb * kMB + tid;
        out[bidx] = acc + x[(size_t)bidx * kT * kF + (size_t)(kT - 1) * kF];
    }
}

extern "C" void kernel_launch(void* const* d_in, const int* in_sizes, int n_in,
                              void* d_out, int out_size, void* d_ws, size_t ws_size,
                              hipStream_t stream) {
    const float* x    = (const float*)d_in[0];
    const float* W_ih = (const float*)d_in[1];
    const float* W_hh = (const float*)d_in[2];
    const float* b_ih = (const float*)d_in[3];
    const float* b_hh = (const float*)d_in[4];
    const float* W1   = (const float*)d_in[5];
    const float* b1   = (const float*)d_in[6];
    const float* W2   = (const float*)d_in[7];
    const float* b2   = (const float*)d_in[8];
    float* out = (float*)d_out;

    lstm_mfma<<<dim3(kBt / kMB), dim3(256), 0, stream>>>(
        x, W_ih, W_hh, b_ih, b_hh, W1, b1, W2, b2, out);
}